// Round 15
// baseline (515.896 us; speedup 1.0000x reference)
//
#include <hip/hip_runtime.h>
#include <stdint.h>

// 2-layer LSTM, B=64, T=1024, D=512, H=32, fp32 in/out.
// Phase 1: f16 MFMA GEMM (proven R14, ~30us).
// Phase 2: fused 2-layer scan, 1 wave/batch. R15 change: h-state broadcast via
//   LDS (16-lane ds_write + uniform-addr ds_read_b128 -> VGPRs) instead of
//   32x v_readlane -> SGPRs. Removes readlane issue cost AND VALU->SGPR->VALU
//   hazards AND makes all dot2 operands VGPRs (tests whether VOP3P quarter-rate
//   was an SGPR-operand artifact). Reloads software-pipelined behind dots.

#define TT 1024
#define BB 64
#define DD 512
#define HH 32
#define GG 128  // 4*H

typedef _Float16 h2v __attribute__((ext_vector_type(2)));
typedef __fp16 pk2 __attribute__((ext_vector_type(2)));
typedef int int2v __attribute__((ext_vector_type(2)));
typedef _Float16 f16x8 __attribute__((ext_vector_type(8)));
typedef float f32x4 __attribute__((ext_vector_type(4)));

__device__ __forceinline__ uint32_t pack2(float lo, float hi) {
  pk2 p = __builtin_amdgcn_cvt_pkrtz(lo, hi);
  return __builtin_bit_cast(uint32_t, p);
}
__device__ __forceinline__ float dot2(uint32_t a, uint32_t b, float acc) {
  return __builtin_amdgcn_fdot2(__builtin_bit_cast(h2v, a),
                                __builtin_bit_cast(h2v, b), acc, false);
}
__device__ __forceinline__ float fast_rcp(float x) { return __builtin_amdgcn_rcpf(x); }
__device__ __forceinline__ float sigm(float s) { return fast_rcp(1.f + __expf(-s)); }
__device__ __forceinline__ float fast_tanh(float x) {
  return fmaf(2.f, fast_rcp(1.f + __expf(-2.f * x)), -1.f);
}
__device__ __forceinline__ float act_sel(float s, bool ist) {
  float z = ist ? s + s : s;
  float r = fast_rcp(1.f + __expf(-z));
  return ist ? fmaf(2.f, r, -1.f) : r;
}

// xor-32 partner, pure VALU; order-proof XOR extraction (verified R6).
__device__ __forceinline__ float partner32(float x) {
  int xi = __builtin_bit_cast(int, x);
#if __has_builtin(__builtin_amdgcn_permlane32_swap)
  int2v r = __builtin_amdgcn_permlane32_swap(xi, xi, false, false);
  return __builtin_bit_cast(float, r.x ^ r.y ^ xi);
#else
  int a = xi, b = xi;
  asm("v_permlane32_swap_b32 %0, %1" : "+v"(a), "+v"(b));
  return __builtin_bit_cast(float, a ^ b ^ xi);
#endif
}

// xor-1 neighbor exchange via DPP quad_perm [1,0,3,2]
__device__ __forceinline__ float xor1_dpp(float x) {
  int xi = __builtin_bit_cast(int, x);
  int r = __builtin_amdgcn_update_dpp(xi, xi, 0xB1, 0xF, 0xF, true);
  return __builtin_bit_cast(float, r);
}

// ---------------- Phase 1: f16 MFMA GEMM (proven R14) ----------------
__global__ __launch_bounds__(256) void xg_gemm_mfma(const float* __restrict__ x,
                                                    const float* __restrict__ W,
                                                    const float* __restrict__ bih,
                                                    const float* __restrict__ bhh,
                                                    float* __restrict__ outp) {
  __shared__ _Float16 lxs[128][40];
  __shared__ _Float16 lws[128][40];
  const int tid = threadIdx.x;
  const int m0 = blockIdx.x * 128;
  const int sr = tid >> 1;
  const int sk = (tid & 1) * 16;
  const int w = tid >> 6;
  const int wm = (w >> 1) * 64;
  const int wn = (w & 1) * 64;
  const int lane = tid & 63;
  const int lr = lane & 15;
  const int lk = (lane >> 4) * 8;

  f32x4 acc[4][4];
#pragma unroll
  for (int i = 0; i < 4; ++i)
#pragma unroll
    for (int j = 0; j < 4; ++j) acc[i][j] = (f32x4){0.f, 0.f, 0.f, 0.f};

  for (int k0 = 0; k0 < DD; k0 += 32) {
#pragma unroll
    for (int c = 0; c < 4; ++c) {
      const float4 xv = *(const float4*)(x + (size_t)(m0 + sr) * DD + k0 + sk + c * 4);
      uint2 px;
      px.x = pack2(xv.x, xv.y);
      px.y = pack2(xv.z, xv.w);
      *(uint2*)&lxs[sr][sk + c * 4] = px;
      const float4 wv = *(const float4*)(W + (size_t)sr * DD + k0 + sk + c * 4);
      uint2 pw;
      pw.x = pack2(wv.x, wv.y);
      pw.y = pack2(wv.z, wv.w);
      *(uint2*)&lws[sr][sk + c * 4] = pw;
    }
    __syncthreads();
    f16x8 af[4], bf[4];
#pragma unroll
    for (int s = 0; s < 4; ++s) {
      af[s] = *(const f16x8*)&lxs[wm + s * 16 + lr][lk];
      bf[s] = *(const f16x8*)&lws[wn + s * 16 + lr][lk];
    }
#pragma unroll
    for (int mi = 0; mi < 4; ++mi)
#pragma unroll
      for (int ni = 0; ni < 4; ++ni)
        acc[mi][ni] = __builtin_amdgcn_mfma_f32_16x16x32_f16(af[mi], bf[ni],
                                                             acc[mi][ni], 0, 0, 0);
    __syncthreads();
  }
  const int rq = (lane >> 4) * 4;
#pragma unroll
  for (int ni = 0; ni < 4; ++ni) {
    const int g = wn + ni * 16 + lr;
    const float bsum = bih[g] + bhh[g];
#pragma unroll
    for (int mi = 0; mi < 4; ++mi) {
      const int mbase = m0 + wm + mi * 16 + rq;
#pragma unroll
      for (int q = 0; q < 4; ++q)
        outp[(size_t)(mbase + q) * GG + g] = acc[mi][ni][q] + bsum;
    }
  }
}

// ---------------- Phase 2: scan with LDS h-broadcast ----------------
__global__ __launch_bounds__(64)
__attribute__((amdgpu_waves_per_eu(1)))
void lstm_scan(const float* __restrict__ xg,
               const float* __restrict__ Whh0,
               const float* __restrict__ Wih1,
               const float* __restrict__ Whh1,
               const float* __restrict__ bih1,
               const float* __restrict__ bhh1,
               float* __restrict__ out) {
  __shared__ uint32_t hbuf[32];  // [0..15] h0 f16-pairs, [16..31] h1 f16-pairs
  const int l = threadIdx.x;
  const int j = l & 31;
  const int hi = l >> 5;
  const int b = blockIdx.x;
  const int gA = j + 64 * hi;
  const int gB = gA + 32;

  uint32_t w0A[16], w0B[16], wiA[16], whA[16], wiB[16], whB[16];
#pragma unroll
  for (int q = 0; q < 8; ++q) {
    float4 a = *(const float4*)(Whh0 + (size_t)gA * HH + q * 4);
    float4 c = *(const float4*)(Whh0 + (size_t)gB * HH + q * 4);
    w0A[2 * q] = pack2(a.x, a.y); w0A[2 * q + 1] = pack2(a.z, a.w);
    w0B[2 * q] = pack2(c.x, c.y); w0B[2 * q + 1] = pack2(c.z, c.w);
    float4 d = *(const float4*)(Wih1 + (size_t)gA * HH + q * 4);
    float4 e = *(const float4*)(Wih1 + (size_t)gB * HH + q * 4);
    wiA[2 * q] = pack2(d.x, d.y); wiA[2 * q + 1] = pack2(d.z, d.w);
    wiB[2 * q] = pack2(e.x, e.y); wiB[2 * q + 1] = pack2(e.z, e.w);
    float4 f = *(const float4*)(Whh1 + (size_t)gA * HH + q * 4);
    float4 g = *(const float4*)(Whh1 + (size_t)gB * HH + q * 4);
    whA[2 * q] = pack2(f.x, f.y); whA[2 * q + 1] = pack2(f.z, f.w);
    whB[2 * q] = pack2(g.x, g.y); whB[2 * q + 1] = pack2(g.z, g.w);
  }
#pragma unroll
  for (int k = 0; k < 16; ++k) {
    asm volatile("" : "+v"(w0A[k]));
    asm volatile("" : "+v"(w0B[k]));
    asm volatile("" : "+v"(wiA[k]));
    asm volatile("" : "+v"(wiB[k]));
    asm volatile("" : "+v"(whA[k]));
    asm volatile("" : "+v"(whB[k]));
  }
  const float b1A = bih1[gA] + bhh1[gA];
  const float b1B = bih1[gB] + bhh1[gB];

  uint32_t h0v[16], h1v[16];  // per-lane VGPR copies (uniform values)
#pragma unroll
  for (int k = 0; k < 16; ++k) { h0v[k] = 0u; h1v[k] = 0u; }
  if (l < 32) hbuf[l] = 0u;
  float c0 = 0.f, c1 = 0.f;

  const float* xgp = xg + (size_t)b * TT * GG;
  float* outp = out + (size_t)b * TT * HH;

  float xA[4], xB[4];
#pragma unroll
  for (int u = 0; u < 4; ++u) {
    xA[u] = xgp[u * GG + gA];
    xB[u] = xgp[u * GG + gB];
  }

  const bool wrt = (!hi) && ((j & 1) == 0);  // 16 writer lanes (even j, lo half)
  const uint4* hb4 = (const uint4*)hbuf;

  for (int tb = 0; tb < TT; tb += 4) {
#pragma unroll
    for (int u = 0; u < 4; ++u) {
      const int t = tb + u;
      float sA0 = xA[u], sB0 = xB[u];
      const int tp = (t + 4 < TT) ? (t + 4) : (TT - 1);
      xA[u] = xgp[(size_t)tp * GG + gA];
      xB[u] = xgp[(size_t)tp * GG + gB];
      // ---- layer0 dots (h0v = h0[t-1]) ----
      float pA = 0.f, pB = 0.f;
#pragma unroll
      for (int k = 0; k < 16; k += 2) {
        sA0 = dot2(w0A[k], h0v[k], sA0);
        pA  = dot2(w0A[k + 1], h0v[k + 1], pA);
        sB0 = dot2(w0B[k], h0v[k], sB0);
        pB  = dot2(w0B[k + 1], h0v[k + 1], pB);
      }
      sA0 += pA; sB0 += pB;
      // ---- reload h1v (written at end of prev iter; gap = layer0 dots) ----
      {
        uint4 r0 = hb4[4], r1 = hb4[5], r2 = hb4[6], r3 = hb4[7];
        h1v[0] = r0.x; h1v[1] = r0.y; h1v[2] = r0.z; h1v[3] = r0.w;
        h1v[4] = r1.x; h1v[5] = r1.y; h1v[6] = r1.z; h1v[7] = r1.w;
        h1v[8] = r2.x; h1v[9] = r2.y; h1v[10] = r2.z; h1v[11] = r2.w;
        h1v[12] = r3.x; h1v[13] = r3.y; h1v[14] = r3.z; h1v[15] = r3.w;
      }
      // ---- layer1 dots for step t-1 (h0v=h0[t-1], h1v=h1[t-2]) ----
      float sA1 = b1A, sB1 = b1B, qA = 0.f, qB = 0.f;
#pragma unroll
      for (int k = 0; k < 16; k += 2) {
        sA1 = dot2(wiA[k], h0v[k], sA1);
        qA  = dot2(wiA[k + 1], h0v[k + 1], qA);
        sB1 = dot2(wiB[k], h0v[k], sB1);
        qB  = dot2(wiB[k + 1], h0v[k + 1], qB);
        sA1 = dot2(whA[k], h1v[k], sA1);
        qA  = dot2(whA[k + 1], h1v[k + 1], qA);
        sB1 = dot2(whB[k], h1v[k], sB1);
        qB  = dot2(whB[k + 1], h1v[k + 1], qB);
      }
      sA1 += qA; sB1 += qB;
      // ---- layer0 combine -> h0[t], write to LDS ----
      {
        float aA = act_sel(sA0, hi != 0);
        float aB = sigm(sB0);
        float pAx = partner32(aA);
        float pBx = partner32(aB);
        float gi = hi ? pAx : aA;
        float gf = hi ? pBx : aB;
        float gg = hi ? aA : pAx;
        float go = hi ? aB : pBx;
        c0 = fmaf(gf, c0, gi * gg);
        float h = go * fast_tanh(c0);
        float oth = xor1_dpp(h);
        float lo = (j & 1) ? oth : h;
        float hh = (j & 1) ? h : oth;
        uint32_t pk = pack2(lo, hh);
        if (wrt) hbuf[j >> 1] = pk;
      }
      // ---- layer1 combine for step t-1, write to LDS ----
      if (t > 0) {
        float aA = act_sel(sA1, hi != 0);
        float aB = sigm(sB1);
        float pAx = partner32(aA);
        float pBx = partner32(aB);
        float gi = hi ? pAx : aA;
        float gf = hi ? pBx : aB;
        float gg = hi ? aA : pAx;
        float go = hi ? aB : pBx;
        c1 = fmaf(gf, c1, gi * gg);
        float h = go * fast_tanh(c1);
        if (!hi) outp[(size_t)(t - 1) * HH + j] = h;
        float oth = xor1_dpp(h);
        float lo = (j & 1) ? oth : h;
        float hh = (j & 1) ? h : oth;
        uint32_t pk = pack2(lo, hh);
        if (wrt) hbuf[16 + (j >> 1)] = pk;
      }
      // ---- reload h0v (gap from write = layer1 combine) ----
      {
        uint4 r0 = hb4[0], r1 = hb4[1], r2 = hb4[2], r3 = hb4[3];
        h0v[0] = r0.x; h0v[1] = r0.y; h0v[2] = r0.z; h0v[3] = r0.w;
        h0v[4] = r1.x; h0v[5] = r1.y; h0v[6] = r1.z; h0v[7] = r1.w;
        h0v[8] = r2.x; h0v[9] = r2.y; h0v[10] = r2.z; h0v[11] = r2.w;
        h0v[12] = r3.x; h0v[13] = r3.y; h0v[14] = r3.z; h0v[15] = r3.w;
      }
    }
  }
  // ---- final layer1 step (t = TT-1): h0v=h0[TT-1], h1v from last write ----
  {
    uint4 r0 = hb4[4], r1 = hb4[5], r2 = hb4[6], r3 = hb4[7];
    h1v[0] = r0.x; h1v[1] = r0.y; h1v[2] = r0.z; h1v[3] = r0.w;
    h1v[4] = r1.x; h1v[5] = r1.y; h1v[6] = r1.z; h1v[7] = r1.w;
    h1v[8] = r2.x; h1v[9] = r2.y; h1v[10] = r2.z; h1v[11] = r2.w;
    h1v[12] = r3.x; h1v[13] = r3.y; h1v[14] = r3.z; h1v[15] = r3.w;
    float sA1 = b1A, sB1 = b1B, qA = 0.f, qB = 0.f;
#pragma unroll
    for (int k = 0; k < 16; k += 2) {
      sA1 = dot2(wiA[k], h0v[k], sA1);
      qA  = dot2(wiA[k + 1], h0v[k + 1], qA);
      sB1 = dot2(wiB[k], h0v[k], sB1);
      qB  = dot2(wiB[k + 1], h0v[k + 1], qB);
      sA1 = dot2(whA[k], h1v[k], sA1);
      qA  = dot2(whA[k + 1], h1v[k + 1], qA);
      sB1 = dot2(whB[k], h1v[k], sB1);
      qB  = dot2(whB[k + 1], h1v[k + 1], qB);
    }
    sA1 += qA; sB1 += qB;
    float aA = act_sel(sA1, hi != 0);
    float aB = sigm(sB1);
    float pAx = partner32(aA);
    float pBx = partner32(aB);
    float gi = hi ? pAx : aA;
    float gf = hi ? pBx : aB;
    float gg = hi ? aA : pAx;
    float go = hi ? aB : pBx;
    c1 = fmaf(gf, c1, gi * gg);
    float h = go * fast_tanh(c1);
    if (!hi) outp[(size_t)(TT - 1) * HH + j] = h;
  }
}

extern "C" void kernel_launch(void* const* d_in, const int* in_sizes, int n_in,
                              void* d_out, int out_size, void* d_ws, size_t ws_size,
                              hipStream_t stream) {
  const float* x = (const float*)d_in[0];
  const float* Wih0 = (const float*)d_in[1];
  const float* Whh0 = (const float*)d_in[2];
  const float* bih0 = (const float*)d_in[3];
  const float* bhh0 = (const float*)d_in[4];
  const float* Wih1 = (const float*)d_in[5];
  const float* Whh1 = (const float*)d_in[6];
  const float* bih1 = (const float*)d_in[7];
  const float* bhh1 = (const float*)d_in[8];
  float* out = (float*)d_out;
  float* xg = (float*)d_ws;  // B*T*4H*4 = 33.5 MB scratch

  xg_gemm_mfma<<<dim3((BB * TT) / 128), dim3(256), 0, stream>>>(x, Wih0, bih0, bhh0, xg);
  lstm_scan<<<dim3(BB), dim3(64), 0, stream>>>(xg, Whh0, Wih1, Whh1, bih1, bhh1, out);
}